// Round 1
// baseline (653.176 us; speedup 1.0000x reference)
//
#include <hip/hip_runtime.h>

// SkeletalEncBlock: masked skeletal conv1d(K=3,'same') + offset inject + pair pool + LeakyReLU(0.2)
// x:      [B=128, J*CIN=192, T=4096] fp32
// offset: [B, 72]
// W:      [192, 192, 3]
// b:      [192]
// W_off:  [192, 72]
// out:    [B, 96, T]  (region-pooled channels, r*8+o)

#define NJ    24
#define NCIN  8
#define NCOUT 8
#define KS    3
#define NB    128
#define NT    4096
#define NREG  12          // J/2 pooled regions
#define VT    8           // t-values per thread
#define TPB   256
#define TILE  (TPB * VT)  // 2048
#define NTILES (NT / TILE) // 2
#define NEG_SLOPE 0.2f

__global__ __launch_bounds__(TPB) void skel_enc_kernel(
    const float* __restrict__ x,
    const float* __restrict__ offset,
    const float* __restrict__ W,
    const float* __restrict__ bias,
    const float* __restrict__ Woff,
    float* __restrict__ out)
{
    const int tile = blockIdx.x;
    const int r    = blockIdx.y;   // pooled region 0..11
    const int b    = blockIdx.z;

    // input-joint span for region r: joints [max(2r-1,0), min(2r+2,23)]
    const int jlo  = (2 * r - 1 > 0) ? (2 * r - 1) : 0;
    const int jhi  = (2 * r + 2 < NJ - 1) ? (2 * r + 2) : (NJ - 1);
    const int ncin = (jhi - jlo + 1) * NCIN;   // 24 or 32
    const int c0   = jlo * NCIN;               // global input-channel base

    __shared__ __align__(16) float sW[32 * 24];   // [c_local][o*3+k]  effective pooled+masked weights
    __shared__ float sBias[NCOUT];                // pooled bias + offset injection

    const int tid = threadIdx.x;
    const int j0 = 2 * r, j1 = 2 * r + 1;

    // ---- stage effective weights (pool fold + adjacency mask) ----
    for (int idx = tid; idx < 32 * 24; idx += TPB) {
        const int c   = idx / 24;
        const int rem = idx - c * 24;
        const int o   = rem / 3;
        const int k   = rem - o * 3;
        float val = 0.f;
        if (c < ncin) {
            const int gj = jlo + (c >> 3);         // input joint of this channel
            const int gc = c0 + c;                 // global input channel
            const float w0 = W[(size_t)(j0 * NCOUT + o) * (NJ * NCIN * KS) + gc * KS + k];
            const float w1 = W[(size_t)(j1 * NCOUT + o) * (NJ * NCIN * KS) + gc * KS + k];
            const float m0 = (gj >= j0 - 1 && gj <= j0 + 1) ? 1.f : 0.f;
            const float m1 = (gj >= j1 - 1 && gj <= j1 + 1) ? 1.f : 0.f;
            val = 0.5f * (w0 * m0 + w1 * m1);
        }
        sW[idx] = val;
    }

    // ---- per-(b, region) pooled bias + masked offset injection ----
    if (tid < NCOUT) {
        const int o = tid;
        float acc = 0.5f * (bias[j0 * NCOUT + o] + bias[j1 * NCOUT + o]);
        const float* offb = offset + (size_t)b * (NJ * 3);
        float s0 = 0.f, s1 = 0.f;
        for (int i = 0; i < NJ * 3; ++i) {
            const int ji = i / 3;
            const float ov = offb[i];
            if (ji >= j0 - 1 && ji <= j0 + 1)
                s0 += Woff[(size_t)(j0 * NCOUT + o) * (NJ * 3) + i] * ov;
            if (ji >= j1 - 1 && ji <= j1 + 1)
                s1 += Woff[(size_t)(j1 * NCOUT + o) * (NJ * 3) + i] * ov;
        }
        sBias[o] = acc + 0.5f * (s0 + s1);
    }
    __syncthreads();

    // ---- main conv: thread owns VT consecutive t's, all 8 out channels ----
    const int t0 = tile * TILE + tid * VT;

    float acc[NCOUT][VT];
    #pragma unroll
    for (int o = 0; o < NCOUT; ++o) {
        const float bv = sBias[o];
        #pragma unroll
        for (int v = 0; v < VT; ++v) acc[o][v] = bv;
    }

    const float* xb = x + (size_t)b * (NJ * NCIN) * NT + t0;
    const bool has_lo = (t0 > 0);
    const bool has_hi = (t0 + VT < NT);

    for (int c = 0; c < ncin; ++c) {
        const float* xp = xb + (size_t)(c0 + c) * NT;

        float xv[VT + 2];
        const float4 a0 = *reinterpret_cast<const float4*>(xp);
        const float4 a1 = *reinterpret_cast<const float4*>(xp + 4);
        xv[1] = a0.x; xv[2] = a0.y; xv[3] = a0.z; xv[4] = a0.w;
        xv[5] = a1.x; xv[6] = a1.y; xv[7] = a1.z; xv[8] = a1.w;
        {   // halo loads without OOB: clamp address, zero via select
            const float xm = xp[has_lo ? -1 : 0];
            xv[0] = has_lo ? xm : 0.f;
            const float xq = xp[has_hi ? VT : VT - 1];
            xv[VT + 1] = has_hi ? xq : 0.f;
        }

        float wreg[24];
        {
            float4* wr = reinterpret_cast<float4*>(wreg);
            const float4* sw = reinterpret_cast<const float4*>(&sW[c * 24]);
            #pragma unroll
            for (int q = 0; q < 6; ++q) wr[q] = sw[q];   // broadcast ds_read_b128
        }

        #pragma unroll
        for (int o = 0; o < NCOUT; ++o) {
            #pragma unroll
            for (int k = 0; k < KS; ++k) {
                const float wv = wreg[o * 3 + k];
                #pragma unroll
                for (int v = 0; v < VT; ++v)
                    acc[o][v] = fmaf(wv, xv[v + k], acc[o][v]);
            }
        }
    }

    // ---- LeakyReLU + coalesced float4 stores ----
    float* ob = out + ((size_t)b * (NREG * NCOUT) + r * NCOUT) * NT + t0;
    #pragma unroll
    for (int o = 0; o < NCOUT; ++o) {
        float4 s0, s1;
        float tmp[VT];
        #pragma unroll
        for (int v = 0; v < VT; ++v) {
            const float y = acc[o][v];
            tmp[v] = (y > 0.f) ? y : NEG_SLOPE * y;
        }
        s0.x = tmp[0]; s0.y = tmp[1]; s0.z = tmp[2]; s0.w = tmp[3];
        s1.x = tmp[4]; s1.y = tmp[5]; s1.z = tmp[6]; s1.w = tmp[7];
        float* op = ob + (size_t)o * NT;
        *reinterpret_cast<float4*>(op)     = s0;
        *reinterpret_cast<float4*>(op + 4) = s1;
    }
}

extern "C" void kernel_launch(void* const* d_in, const int* in_sizes, int n_in,
                              void* d_out, int out_size, void* d_ws, size_t ws_size,
                              hipStream_t stream) {
    const float* x      = (const float*)d_in[0];
    const float* offset = (const float*)d_in[1];
    const float* W      = (const float*)d_in[2];
    const float* bias   = (const float*)d_in[3];
    const float* Woff   = (const float*)d_in[4];
    float* out = (float*)d_out;

    dim3 grid(NTILES, NREG, NB);
    skel_enc_kernel<<<grid, TPB, 0, stream>>>(x, offset, W, bias, Woff, out);
}